// Round 7
// baseline (2522.800 us; speedup 1.0000x reference)
//
#include <hip/hip_runtime.h>
#include <math.h>

typedef unsigned short u16;
typedef unsigned int   u32;
typedef __attribute__((ext_vector_type(8))) short s8b;   // 8 bf16 (4 VGPR) MFMA frag
typedef __attribute__((ext_vector_type(4))) float f32x4; // MFMA acc

#define MFMA(a,b,c) __builtin_amdgcn_mfma_f32_16x16x32_bf16((a),(b),(c),0,0,0)

__device__ __forceinline__ float bf2f(u16 v){ return __uint_as_float(((u32)v)<<16); }
__device__ __forceinline__ u16 f2bf(float f){
    u32 u = __float_as_uint(f);
    u32 r = ((u>>16)&1u) + 0x7fffu;
    return (u16)((u + r)>>16);
}
__device__ __forceinline__ float rcp_(float x){ return __builtin_amdgcn_rcpf(x); }
__device__ __forceinline__ float sigm_(float x){ return rcp_(1.f + __expf(-x)); }
__device__ __forceinline__ float tanh_(float x){ return 1.f - 2.f*rcp_(1.f + __expf(2.f*x)); }

// ---------------- P0: weight prep (pad K 198->256, f32->bf16) ----------------
__global__ __launch_bounds__(256) void k_prep(const float* __restrict__ wihf,
    const float* __restrict__ wihb, const float* __restrict__ whhf,
    u16* __restrict__ wihf_p, u16* __restrict__ wihb_p, u16* __restrict__ whh_b){
  int idx = blockIdx.x*256 + threadIdx.x;
  if (idx >= 262144) return;
  int n = idx>>8, k = idx&255;
  wihf_p[idx] = (k<198)? f2bf(wihf[n*198+k]) : (u16)0;
  wihb_p[idx] = (k<198)? f2bf(wihb[n*198+k]) : (u16)0;
  whh_b[idx]  = f2bf(whhf[idx]);
}

// ---------------- K1: haversine + mercator normalize ----------------
__global__ __launch_bounds__(256) void k_pre(const float* __restrict__ x1,
    const float* __restrict__ x2, const float* __restrict__ dtime,
    float* __restrict__ xn, float* __restrict__ x3n){
  const float D2R = 0.017453292519943295f;
  const float R2D = 57.29577951308232f;
  const float RM  = 6378137.0f;
  const float PI4 = 0.7853981633974483f;
  int b = blockIdx.x, tid = threadIdx.x;
  __shared__ float red[256];
  float av[4], bv[4];
  #pragma unroll
  for (int j=0;j<2;j++){
    int l = tid + j*256;
    float la = x1[((size_t)b*512+l)*6+0], lo = x1[((size_t)b*512+l)*6+1];
    av[j]   = RM*(lo*D2R);
    bv[j]   = RM*logf(tanf(PI4 + la*D2R*0.5f));
    la = x2[((size_t)b*512+l)*6+0]; lo = x2[((size_t)b*512+l)*6+1];
    av[2+j] = RM*(lo*D2R);
    bv[2+j] = RM*logf(tanf(PI4 + la*D2R*0.5f));
  }
  float mxA,mnA,mxB,mnB,v;
  v = fmaxf(fmaxf(av[0],av[1]),fmaxf(av[2],av[3]));
  red[tid]=v; __syncthreads();
  for (int s=128;s;s>>=1){ if (tid<s) red[tid]=fmaxf(red[tid],red[tid+s]); __syncthreads(); }
  mxA = red[0]; __syncthreads();
  v = fminf(fminf(av[0],av[1]),fminf(av[2],av[3]));
  red[tid]=v; __syncthreads();
  for (int s=128;s;s>>=1){ if (tid<s) red[tid]=fminf(red[tid],red[tid+s]); __syncthreads(); }
  mnA = red[0]; __syncthreads();
  v = fmaxf(fmaxf(bv[0],bv[1]),fmaxf(bv[2],bv[3]));
  red[tid]=v; __syncthreads();
  for (int s=128;s;s>>=1){ if (tid<s) red[tid]=fmaxf(red[tid],red[tid+s]); __syncthreads(); }
  mxB = red[0]; __syncthreads();
  v = fminf(fminf(bv[0],bv[1]),fminf(bv[2],bv[3]));
  red[tid]=v; __syncthreads();
  for (int s=128;s;s>>=1){ if (tid<s) red[tid]=fminf(red[tid],red[tid+s]); __syncthreads(); }
  mnB = red[0];
  float dA = mxA-mnA+1e-8f, dB = mxB-mnB+1e-8f;
  float lat1 = x1[((size_t)b*512+511)*6+0], lon1 = x1[((size_t)b*512+511)*6+1];
  float lat2 = x2[((size_t)b*512+0)*6+0],   lon2 = x2[((size_t)b*512+0)*6+1];
  float la1=lat1*D2R, lo1=lon1*D2R, la2=lat2*D2R, lo2=lon2*D2R;
  float dlon=lo2-lo1, dlat=la2-la1;
  float sdlat=sinf(dlat*0.5f), sdlon=sinf(dlon*0.5f);
  float ah = sdlat*sdlat + cosf(la1)*cosf(la2)*sdlon*sdlon;
  float dist = 2.f*asinf(sqrtf(ah))*6371.0f;
  float yb = sinf(dlon)*cosf(la2);
  float xb = cosf(la1)*sinf(la2) - sinf(la1)*cosf(la2)*cosf(dlon);
  float brg = fmodf(atan2f(yb,xb)*R2D + 360.f, 360.f)*D2R;
  float dt = dtime[b]; if (dt==0.f) dt = 1.f;
  float speeds = dist/dt*1000.f/0.514444f;
  float vx = speeds*sinf(brg), vy = speeds*cosf(brg);
  #pragma unroll
  for (int j=0;j<2;j++){
    int l = tid + j*256;
    const float* s1 = x1 + ((size_t)b*512+l)*6;
    float* o1p = xn + ((size_t)b*512+l)*6;
    o1p[0] = (av[j]-mnA)/dA; o1p[1] = (bv[j]-mnB)/dB;
    o1p[2]=s1[2]; o1p[3]=s1[3]; o1p[4]=s1[4]; o1p[5]=s1[5];
    const float* s2 = x2 + ((size_t)b*512+l)*6;
    float* o2p = xn + ((size_t)(128+b)*512+l)*6;
    o2p[0] = (av[2+j]-mnA)/dA; o2p[1] = (bv[2+j]-mnB)/dB;
    float c2=s2[2], c3=s2[3], c4=s2[4], c5=s2[5];
    if (l==0){ c2 = (speeds!=0.f)?speeds:c2; c4 = (vx!=0.f)?vx:c4; c5 = (vy!=0.f)?vy:c5; }
    o2p[2]=c2; o2p[3]=c3; o2p[4]=c4; o2p[5]=c5;
  }
  if (tid==0){
    const float* r0 = x1 + ((size_t)b*512+511)*6;
    const float* r1 = x2 + ((size_t)b*512+0)*6;
    float* t0 = x3n + (size_t)b*12;
    float* t1 = t0 + 6;
    t0[0] = (RM*logf(tanf(PI4 + r0[0]*D2R*0.5f)) - mnA)/dA;
    t0[1] = (RM*(r0[1]*D2R) - mnB)/dB;
    t0[2]=r0[2]; t0[3]=r0[3]; t0[4]=r0[4]; t0[5]=r0[5];
    t1[0] = (RM*logf(tanf(PI4 + r1[0]*D2R*0.5f)) - mnA)/dA;
    t1[1] = (RM*(r1[1]*D2R) - mnB)/dB;
    float c2=r1[2], c4=r1[4], c5=r1[5];
    c2 = (speeds!=0.f)?speeds:c2; c4=(vx!=0.f)?vx:c4; c5=(vy!=0.f)?vy:c5;
    t1[2]=c2; t1[3]=r1[3]; t1[4]=c4; t1[5]=c5;
  }
}

// ---------------- K2: conv features -> feat [131072][256] bf16 ----------------
__global__ __launch_bounds__(256) void k_conv(const float* __restrict__ xn,
    const float* __restrict__ w1, const float* __restrict__ b1,
    const float* __restrict__ w3, const float* __restrict__ b3,
    const float* __restrict__ w5, const float* __restrict__ b5,
    u16* __restrict__ feat){
  int bb = blockIdx.x, tid = threadIdx.x;
  __shared__ float xs[516][7];
  __shared__ float ws[3648];
  for (int i=tid;i<516*6;i+=256){ int t=i/6-2, c=i%6;
    xs[i/6][c] = (t>=0 && t<512)? xn[((size_t)bb*512+t)*6+c] : 0.f; }
  for (int i=tid;i<3648;i+=256){
    float w;
    if (i<384) w=w1[i];
    else if (i<1536) w=w3[i-384];
    else if (i<3456) w=w5[i-1536];
    else if (i<3520) w=b1[i-3456];
    else if (i<3584) w=b3[i-3520];
    else w=b5[i-3584];
    ws[i]=w;
  }
  __syncthreads();
  int tl = tid & 127, hh = tid >> 7;
  for (int j=0;j<4;j++){
    int t = tl + j*128;
    u32* fru = (u32*)(feat + ((size_t)bb*512+t)*256);
    for (int p=0;p<16;p++){
      u32 pk=0;
      #pragma unroll
      for (int e=0;e<2;e++){
        int oc = 32*hh + p*2 + e;
        float acc = ws[3456+oc];
        #pragma unroll
        for (int i=0;i<6;i++) acc += xs[t+2][i]*ws[oc*6+i];
        pk |= ((u32)f2bf(fmaxf(acc,0.f)))<<(16*e);
      }
      fru[3+16*hh+p]=pk;
    }
    for (int p=0;p<16;p++){
      u32 pk=0;
      #pragma unroll
      for (int e=0;e<2;e++){
        int oc = 32*hh + p*2 + e;
        float acc = ws[3520+oc];
        #pragma unroll
        for (int k=0;k<3;k++)
          #pragma unroll
          for (int i=0;i<6;i++) acc += xs[t+1+k][i]*ws[384+oc*18+i*3+k];
        pk |= ((u32)f2bf(fmaxf(acc,0.f)))<<(16*e);
      }
      fru[35+16*hh+p]=pk;
    }
    for (int p=0;p<16;p++){
      u32 pk=0;
      #pragma unroll
      for (int e=0;e<2;e++){
        int oc = 32*hh + p*2 + e;
        float acc = ws[3584+oc];
        #pragma unroll
        for (int k=0;k<5;k++)
          #pragma unroll
          for (int i=0;i<6;i++) acc += xs[t+k][i]*ws[1536+oc*30+i*5+k];
        pk |= ((u32)f2bf(fmaxf(acc,0.f)))<<(16*e);
      }
      fru[67+16*hh+p]=pk;
    }
    if (hh==0){
      #pragma unroll
      for (int p=0;p<3;p++){
        u32 pk = (u32)f2bf(xs[t+2][2*p]) | (((u32)f2bf(xs[t+2][2*p+1]))<<16);
        fru[p]=pk;
      }
    } else {
      for (int p=99;p<128;p++) fru[p]=0u;
    }
  }
}

// ---------------- K2c: x3 branch, full f32 path (conv + xg with biases) ----------------
__global__ __launch_bounds__(256) void k_x3fix(const float* __restrict__ x3n,
    const float* __restrict__ w1, const float* __restrict__ b1,
    const float* __restrict__ w3, const float* __restrict__ b3,
    const float* __restrict__ w5, const float* __restrict__ b5,
    const float* __restrict__ wih, const float* __restrict__ bih, const float* __restrict__ bhh,
    float* __restrict__ xg3, float* __restrict__ featF32){
  int row = blockIdx.x, b = row>>1, t = row&1, tid = threadIdx.x;
  __shared__ float fl[224];
  __shared__ float xv[2][6];
  if (tid < 12) (&xv[0][0])[tid] = x3n[(size_t)b*12 + tid];
  __syncthreads();
  if (tid < 198){
    float v;
    if (tid < 6) v = xv[t][tid];
    else if (tid < 70){
      int oc = tid-6; float acc = b1[oc];
      #pragma unroll
      for (int i=0;i<6;i++) acc += xv[t][i]*w1[oc*6+i];
      v = fmaxf(acc,0.f);
    } else if (tid < 134){
      int oc = tid-70; float acc = b3[oc];
      for (int k=0;k<3;k++){ int tt=t+k-1; if (tt>=0&&tt<2)
        for (int i=0;i<6;i++) acc += xv[tt][i]*w3[oc*18+i*3+k]; }
      v = fmaxf(acc,0.f);
    } else {
      int oc = tid-134; float acc = b5[oc];
      for (int k=0;k<5;k++){ int tt=t+k-2; if (tt>=0&&tt<2)
        for (int i=0;i<6;i++) acc += xv[tt][i]*w5[oc*30+i*5+k]; }
      v = fmaxf(acc,0.f);
    }
    fl[tid]=v;
    featF32[(size_t)row*256+tid]=v;
  }
  __syncthreads();
  int n0 = tid*4;
  float a0=bih[n0]+bhh[n0], a1=bih[n0+1]+bhh[n0+1];
  float a2=bih[n0+2]+bhh[n0+2], a3=bih[n0+3]+bhh[n0+3];
  const float* w0 = wih + (size_t)n0*198;
  for (int k=0;k<198;k++){
    float f = fl[k];
    a0 += w0[k]*f; a1 += w0[198+k]*f; a2 += w0[396+k]*f; a3 += w0[594+k]*f;
  }
  float* op = xg3 + ((size_t)(t*128+b)<<10) + n0;
  op[0]=a0; op[1]=a1; op[2]=a2; op[3]=a3;
}

// ---------------- K2d: x3 backward single step, f32 ----------------
__global__ __launch_bounds__(256) void k_b3fix(const float* __restrict__ featF32,
    const float* __restrict__ wih, const float* __restrict__ bih, const float* __restrict__ bhh,
    float* __restrict__ hb3){
  int b = blockIdx.x, tid = threadIdx.x;
  __shared__ float fl[224];
  if (tid < 198) fl[tid] = featF32[(size_t)(2*b+1)*256 + tid];
  __syncthreads();
  int j = tid;
  float ai=bih[j]+bhh[j], ag=bih[512+j]+bhh[512+j], ao=bih[768+j]+bhh[768+j];
  const float* wi = wih + (size_t)j*198;
  const float* wg = wih + (size_t)(512+j)*198;
  const float* wo = wih + (size_t)(768+j)*198;
  for (int k=0;k<198;k++){
    float f = fl[k];
    ai += wi[k]*f; ag += wg[k]*f; ao += wo[k]*f;
  }
  float c = sigm_(ai)*tanh_(ag);
  hb3[(size_t)b*256 + j] = sigm_(ao)*tanh_(c);
}

// ---------------- K3: xg GEMM 128x128 tile, BK=64 -> bf16 out, LSTM-ordered layout ----------------
__global__ __launch_bounds__(256) void k_gemm2(const u16* __restrict__ Wp,
    const u16* __restrict__ F, const float* __restrict__ bih, const float* __restrict__ bhh,
    u16* __restrict__ outp, int t0){
  __shared__ u16 Wl[8192];  // [128][64] bf16, XOR-swizzled
  __shared__ u16 Fl[8192];
  int tid = threadIdx.x, wv = tid>>6, ln = tid&63;
  int kg = ln>>4, l15 = ln&15;
  int mb = blockIdx.x>>3, nb = blockIdx.x&7;
  int r = tid>>1, koffB = (tid&1)*64;
  int xr = (r&7)<<4;
  int mrow = mb*128 + r;
  int bbs = mrow&255, tls = mrow>>8;
  size_t frow = (size_t)bbs*512 + t0 + tls;
  const u16* gW = Wp + ((size_t)(nb*128 + r)<<8) + (koffB>>1);
  const u16* gF = F + (frow<<8) + (koffB>>1);
  f32x4 acc[4][4];
  #pragma unroll
  for (int wi=0;wi<4;wi++)
    #pragma unroll
    for (int fi=0;fi<4;fi++) acc[wi][fi] = (f32x4){0.f,0.f,0.f,0.f};
  int rowA = (wv&1)*64 + l15;
  int rowB = (wv>>1)*64 + l15;
  int xfr = (l15&7)<<4;
  for (int kt=0; kt<4; ++kt){
    uint4 wv4[4], fv4[4];
    #pragma unroll
    for (int q=0;q<4;q++){
      wv4[q] = *(const uint4*)(gW + kt*64 + q*8);
      fv4[q] = *(const uint4*)(gF + kt*64 + q*8);
    }
    if (kt) __syncthreads();
    #pragma unroll
    for (int q=0;q<4;q++){
      int byt = r*128 + ((koffB + q*16) ^ xr);
      *(uint4*)((char*)Wl + byt) = wv4[q];
      *(uint4*)((char*)Fl + byt) = fv4[q];
    }
    __syncthreads();
    #pragma unroll
    for (int ki=0;ki<2;ki++){
      s8b af[4], bfv[4];
      int kb = (ki*64 + kg*16) ^ xfr;
      #pragma unroll
      for (int wi=0;wi<4;wi++) af[wi]  = *(const s8b*)((char*)Wl + (rowA+wi*16)*128 + kb);
      #pragma unroll
      for (int fi=0;fi<4;fi++) bfv[fi] = *(const s8b*)((char*)Fl + (rowB+fi*16)*128 + kb);
      #pragma unroll
      for (int wi=0;wi<4;wi++)
        #pragma unroll
        for (int fi=0;fi<4;fi++)
          acc[wi][fi] = MFMA(af[wi], bfv[fi], acc[wi][fi]);
    }
  }
  #pragma unroll
  for (int wi=0;wi<4;wi++){
    int n0 = nb*128 + (wv&1)*64 + wi*16 + kg*4;
    float4 b1v = *(const float4*)(bih + n0);
    float4 b2v = *(const float4*)(bhh + n0);
    float bs0=b1v.x+b2v.x, bs1=b1v.y+b2v.y, bs2=b1v.z+b2v.z, bs3=b1v.w+b2v.w;
    int gt = n0>>8, jin = n0&255;
    int lwv = jin>>5, ljt = (jin>>4)&1, lkg = (jin>>2)&3;
    int csub = ((ljt*4+gt)*4+lkg)*64;
    #pragma unroll
    for (int fi=0;fi<4;fi++){
      int m = mb*128 + (wv>>1)*64 + fi*16 + l15;
      int bb = m&255, tl = m>>8;
      size_t e = (((size_t)tl*16 + (bb>>4))*8 + lwv)*2048 + csub + (bb&15)*4;
      uint2 pv;
      pv.x = (u32)f2bf(acc[wi][fi][0]+bs0) | (((u32)f2bf(acc[wi][fi][1]+bs1))<<16);
      pv.y = (u32)f2bf(acc[wi][fi][2]+bs2) | (((u32)f2bf(acc[wi][fi][3]+bs3))<<16);
      *(uint2*)(outp + e) = pv;
    }
  }
}

// ---------------- K4: backward single step (main), 512 thr ----------------
__global__ __launch_bounds__(512,1) void k_bstep(const u16* __restrict__ Wp,
    const float* __restrict__ bih, const float* __restrict__ bhh,
    const u16* __restrict__ feat, int row_stride, int row_off,
    float* __restrict__ hout){
  int tid = threadIdx.x, wv = tid>>6, ln = tid&63;
  int bcol = ln&15, kg = ln>>4;
  int bbase = blockIdx.x*16, jb = wv*32;
  size_t frowb = (size_t)(bbase+bcol)*row_stride + row_off;
  s8b ff[8];
  #pragma unroll
  for (int ki=0;ki<8;ki++) ff[ki] = *(const s8b*)(feat + frowb*256 + ki*32 + kg*8);
  const int gts[3] = {0,2,3};
  f32x4 acc[3][2];
  #pragma unroll
  for (int g3=0;g3<3;g3++)
    #pragma unroll
    for (int jt=0;jt<2;jt++)
      #pragma unroll
      for (int rr=0;rr<4;rr++){
        int n = gts[g3]*256 + jb + jt*16 + kg*4 + rr;
        acc[g3][jt][rr] = bih[n]+bhh[n];
      }
  #pragma unroll
  for (int ki=0;ki<8;ki++)
    #pragma unroll
    for (int g3=0;g3<3;g3++)
      #pragma unroll
      for (int jt=0;jt<2;jt++){
        s8b wfv = *(const s8b*)(Wp + ((size_t)(gts[g3]*256 + jb + jt*16 + bcol)<<8) + ki*32 + kg*8);
        acc[g3][jt] = MFMA(wfv, ff[ki], acc[g3][jt]);
      }
  #pragma unroll
  for (int jt=0;jt<2;jt++)
    #pragma unroll
    for (int rr=0;rr<4;rr++){
      float ig = sigm_(acc[0][jt][rr]);
      float gg = tanh_(acc[1][jt][rr]);
      float og = sigm_(acc[2][jt][rr]);
      float c  = ig*gg;
      hout[(size_t)(bbase+bcol)*256 + jb + jt*16 + kg*4 + rr] = og*tanh_(c);
    }
}

// ---------------- K5a: forward LSTM recurrence, bf16 xg, 1 block/CU (256-reg budget) ----------------
// launch_bounds(512,1): grid is only 16 WGs, so 1 block/CU regardless; the ,1 lets the
// allocator keep wf[3][2][8] (192 regs) resident in AGPRs instead of reloading from L2 each step.
__global__ __launch_bounds__(512,1) void k_lstm2b(
    const u16* __restrict__ Whh,      // [1024][256] bf16
    const u16* __restrict__ xgc,      // bf16, [t][wg][wv][2048] layout, biases folded
    int T, int first, int last,
    u16* __restrict__ hstate, float* __restrict__ cstate, float* __restrict__ hout){
  __shared__ u16 oW[65536];           // o-gate W [256][256], XOR-swizzled (128KB)
  __shared__ u16 hb[2][4096];         // h dbuf [16][256], XOR-swizzled (16KB)
  int tid = threadIdx.x, wv = tid>>6, ln = tid&63;
  int bcol = ln&15, kg = ln>>4;
  int bbase = blockIdx.x*16, jb = wv*32;
  int xb = (bcol&7)<<4;
  for (int c = tid; c < 8192; c += 512){
    int j = c>>5, kc = c&31;
    uint4 v = *(const uint4*)(Whh + ((size_t)(768+j)<<8) + (kc<<3));
    int byt = (j<<9) + ((kc<<4) ^ ((j&7)<<4));
    *(uint4*)((char*)oW + byt) = v;
  }
  {
    int c = tid;
    int b = c>>5, kc = c&31;
    uint4 v;
    if (first) v = (uint4){0u,0u,0u,0u};
    else v = *(const uint4*)(hstate + ((size_t)(bbase+b)<<8) + (kc<<3));
    int byt = (b<<9) + ((kc<<4) ^ ((b&7)<<4));
    *(uint4*)((char*)hb[0] + byt) = v;
  }
  s8b wf[3][2][8];
  #pragma unroll
  for (int gt=0;gt<3;gt++)
    #pragma unroll
    for (int jt=0;jt<2;jt++)
      #pragma unroll
      for (int ki=0;ki<8;ki++)
        wf[gt][jt][ki] = *(const s8b*)(Whh + ((size_t)(gt*256 + jb + jt*16 + bcol)<<8) + ki*32 + kg*8);
  float cst[2][4];
  #pragma unroll
  for (int jt=0;jt<2;jt++)
    #pragma unroll
    for (int rr=0;rr<4;rr++)
      cst[jt][rr] = first ? 0.f : cstate[((size_t)(bbase+bcol)<<8) + jb + jt*16 + kg*4 + rr];
  const u16* xrow = xgc + ((size_t)blockIdx.x*8 + wv)*2048 + kg*64 + bcol*4;
  uint2 xva[8];
  #pragma unroll
  for (int jt=0;jt<2;jt++)
    #pragma unroll
    for (int gt=0;gt<4;gt++)
      xva[jt*4+gt] = *(const uint2*)(xrow + (jt*4+gt)*256);
  __syncthreads();
  for (int t=0; t<T; ++t){
    char* hcur = (char*)hb[t&1];
    char* hnxt = (char*)hb[(t&1)^1];
    #pragma unroll
    for (int jt=0;jt<2;jt++){
      f32x4 a0 = {0.f,0.f,0.f,0.f};
      f32x4 a1 = {0.f,0.f,0.f,0.f};
      f32x4 a2 = {0.f,0.f,0.f,0.f};
      f32x4 a3 = {0.f,0.f,0.f,0.f};
      int j2 = jb + jt*16 + bcol;
      #pragma unroll
      for (int ki=0;ki<8;ki++){
        int kbyt = (ki*64 + kg*16) ^ xb;
        s8b hf = *(const s8b*)(hcur + bcol*512 + kbyt);
        a0 = MFMA(wf[0][jt][ki], hf, a0);
        a1 = MFMA(wf[1][jt][ki], hf, a1);
        a2 = MFMA(wf[2][jt][ki], hf, a2);
        s8b of = *(const s8b*)((char*)oW + j2*512 + kbyt);
        a3 = MFMA(of, hf, a3);
      }
      uint2 x0 = xva[jt*4+0], x1v = xva[jt*4+1], x2v = xva[jt*4+2], x3v = xva[jt*4+3];
      float hv0, hv1, hv2, hv3;
      {
        float ig, fg, gg, og, c2;
        ig = sigm_(a0[0]+bf2f((u16)x0.x));  fg = sigm_(a1[0]+bf2f((u16)x1v.x));
        gg = tanh_(a2[0]+bf2f((u16)x2v.x)); og = sigm_(a3[0]+bf2f((u16)x3v.x));
        c2 = fg*cst[jt][0] + ig*gg; cst[jt][0] = c2; hv0 = og*tanh_(c2);
        ig = sigm_(a0[1]+bf2f((u16)(x0.x>>16)));  fg = sigm_(a1[1]+bf2f((u16)(x1v.x>>16)));
        gg = tanh_(a2[1]+bf2f((u16)(x2v.x>>16))); og = sigm_(a3[1]+bf2f((u16)(x3v.x>>16)));
        c2 = fg*cst[jt][1] + ig*gg; cst[jt][1] = c2; hv1 = og*tanh_(c2);
        ig = sigm_(a0[2]+bf2f((u16)x0.y));  fg = sigm_(a1[2]+bf2f((u16)x1v.y));
        gg = tanh_(a2[2]+bf2f((u16)x2v.y)); og = sigm_(a3[2]+bf2f((u16)x3v.y));
        c2 = fg*cst[jt][2] + ig*gg; cst[jt][2] = c2; hv2 = og*tanh_(c2);
        ig = sigm_(a0[3]+bf2f((u16)(x0.y>>16)));  fg = sigm_(a1[3]+bf2f((u16)(x1v.y>>16)));
        gg = tanh_(a2[3]+bf2f((u16)(x2v.y>>16))); og = sigm_(a3[3]+bf2f((u16)(x3v.y>>16)));
        c2 = fg*cst[jt][3] + ig*gg; cst[jt][3] = c2; hv3 = og*tanh_(c2);
      }
      if (last && t==T-1){
        float* op = hout + ((size_t)(bbase+bcol)<<8) + jb + jt*16 + kg*4;
        op[0]=hv0; op[1]=hv1; op[2]=hv2; op[3]=hv3;
      }
      uint2 hw;
      hw.x = (u32)f2bf(hv0) | (((u32)f2bf(hv1))<<16);
      hw.y = (u32)f2bf(hv2) | (((u32)f2bf(hv3))<<16);
      int wj = (jb + jt*16 + kg*4)*2;
      *(uint2*)(hnxt + bcol*512 + (wj ^ xb)) = hw;
    }
    if (t+1 < T){
      const u16* xp = xrow + (size_t)(t+1)*262144;
      #pragma unroll
      for (int jt=0;jt<2;jt++)
        #pragma unroll
        for (int gt=0;gt<4;gt++)
          xva[jt*4+gt] = *(const uint2*)(xp + (jt*4+gt)*256);
    }
    __syncthreads();
  }
  if (!last){
    char* hfin = (char*)hb[T&1];
    #pragma unroll
    for (int jt=0;jt<2;jt++){
      int wj = jb + jt*16 + kg*4;
      uint2 hw = *(const uint2*)(hfin + bcol*512 + ((wj*2) ^ xb));
      *(uint2*)(hstate + ((size_t)(bbase+bcol)<<8) + wj) = hw;
      float* cp = cstate + ((size_t)(bbase+bcol)<<8) + wj;
      cp[0]=cst[jt][0]; cp[1]=cst[jt][1]; cp[2]=cst[jt][2]; cp[3]=cst[jt][3];
    }
  }
}

// ---------------- K5b: forward LSTM recurrence, f32 xg (x3 branch only, T=2) ----------------
__global__ __launch_bounds__(512,1) void k_lstm2f(
    const u16* __restrict__ Whh,
    const float* __restrict__ xgc,    // [T][nbb][1024] f32
    int T, int nbb, float* __restrict__ hout){
  __shared__ u16 oW[65536];
  __shared__ u16 hb[2][4096];
  int tid = threadIdx.x, wv = tid>>6, ln = tid&63;
  int bcol = ln&15, kg = ln>>4;
  int bbase = blockIdx.x*16, jb = wv*32;
  int xb = (bcol&7)<<4;
  for (int c = tid; c < 8192; c += 512){
    int j = c>>5, kc = c&31;
    uint4 v = *(const uint4*)(Whh + ((size_t)(768+j)<<8) + (kc<<3));
    int byt = (j<<9) + ((kc<<4) ^ ((j&7)<<4));
    *(uint4*)((char*)oW + byt) = v;
  }
  {
    int c = tid;
    int b = c>>5, kc = c&31;
    uint4 v = (uint4){0u,0u,0u,0u};
    int byt = (b<<9) + ((kc<<4) ^ ((b&7)<<4));
    *(uint4*)((char*)hb[0] + byt) = v;
  }
  s8b wf[3][2][8];
  #pragma unroll
  for (int gt=0;gt<3;gt++)
    #pragma unroll
    for (int jt=0;jt<2;jt++)
      #pragma unroll
      for (int ki=0;ki<8;ki++)
        wf[gt][jt][ki] = *(const s8b*)(Whh + ((size_t)(gt*256 + jb + jt*16 + bcol)<<8) + ki*32 + kg*8);
  float cst[2][4];
  #pragma unroll
  for (int jt=0;jt<2;jt++)
    #pragma unroll
    for (int rr=0;rr<4;rr++) cst[jt][rr] = 0.f;
  __syncthreads();
  const float* xrow = xgc + ((size_t)(bbase+bcol)<<10) + jb;
  for (int t=0; t<T; ++t){
    const float* xp = xrow + (size_t)t*nbb*1024;
    char* hcur = (char*)hb[t&1];
    char* hnxt = (char*)hb[(t&1)^1];
    #pragma unroll
    for (int jt=0;jt<2;jt++){
      float4 xv0 = *(const float4*)(xp + 0*256 + jt*16 + kg*4);
      float4 xv1 = *(const float4*)(xp + 1*256 + jt*16 + kg*4);
      float4 xv2 = *(const float4*)(xp + 2*256 + jt*16 + kg*4);
      float4 xv3 = *(const float4*)(xp + 3*256 + jt*16 + kg*4);
      f32x4 a0 = {0.f,0.f,0.f,0.f};
      f32x4 a1 = {0.f,0.f,0.f,0.f};
      f32x4 a2 = {0.f,0.f,0.f,0.f};
      f32x4 a3 = {0.f,0.f,0.f,0.f};
      int j2 = jb + jt*16 + bcol;
      #pragma unroll
      for (int ki=0;ki<8;ki++){
        int kbyt = (ki*64 + kg*16) ^ xb;
        s8b hf = *(const s8b*)(hcur + bcol*512 + kbyt);
        a0 = MFMA(wf[0][jt][ki], hf, a0);
        a1 = MFMA(wf[1][jt][ki], hf, a1);
        a2 = MFMA(wf[2][jt][ki], hf, a2);
        s8b of = *(const s8b*)((char*)oW + j2*512 + kbyt);
        a3 = MFMA(of, hf, a3);
      }
      float hv0, hv1, hv2, hv3;
      {
        float ig, fg, gg, og, c2;
        ig = sigm_(a0[0]+xv0.x); fg = sigm_(a1[0]+xv1.x); gg = tanh_(a2[0]+xv2.x); og = sigm_(a3[0]+xv3.x);
        c2 = fg*cst[jt][0] + ig*gg; cst[jt][0] = c2; hv0 = og*tanh_(c2);
        ig = sigm_(a0[1]+xv0.y); fg = sigm_(a1[1]+xv1.y); gg = tanh_(a2[1]+xv2.y); og = sigm_(a3[1]+xv3.y);
        c2 = fg*cst[jt][1] + ig*gg; cst[jt][1] = c2; hv1 = og*tanh_(c2);
        ig = sigm_(a0[2]+xv0.z); fg = sigm_(a1[2]+xv1.z); gg = tanh_(a2[2]+xv2.z); og = sigm_(a3[2]+xv3.z);
        c2 = fg*cst[jt][2] + ig*gg; cst[jt][2] = c2; hv2 = og*tanh_(c2);
        ig = sigm_(a0[3]+xv0.w); fg = sigm_(a1[3]+xv1.w); gg = tanh_(a2[3]+xv2.w); og = sigm_(a3[3]+xv3.w);
        c2 = fg*cst[jt][3] + ig*gg; cst[jt][3] = c2; hv3 = og*tanh_(c2);
      }
      if (t==T-1){
        float* op = hout + ((size_t)(bbase+bcol)<<8) + jb + jt*16 + kg*4;
        op[0]=hv0; op[1]=hv1; op[2]=hv2; op[3]=hv3;
      }
      uint2 hw;
      hw.x = (u32)f2bf(hv0) | (((u32)f2bf(hv1))<<16);
      hw.y = (u32)f2bf(hv2) | (((u32)f2bf(hv3))<<16);
      int wj = (jb + jt*16 + kg*4)*2;
      *(uint2*)(hnxt + bcol*512 + (wj ^ xb)) = hw;
    }
    __syncthreads();
  }
}

// ---------------- K6: head ----------------
__global__ __launch_bounds__(256) void k_head(const float* __restrict__ hfo,
    const float* __restrict__ hb12, const float* __restrict__ h3f, const float* __restrict__ hb3,
    const float* __restrict__ fc1w, const float* __restrict__ fc1b,
    const float* __restrict__ fc2w, const float* __restrict__ fc2b,
    float* __restrict__ out){
  int g = blockIdx.x, tid = threadIdx.x;
  __shared__ float dl[4][1024];
  __shared__ float o1s[4][512];
  for (int q=0;q<4;q++){
    int b = g*4+q;
    for (int idx=tid; idx<1024; idx+=256){
      int sec = idx>>8, j = idx&255;
      float vv;
      if (sec==0)      vv = fabsf(hfo[(size_t)b*256+j]  - hfo[(size_t)(128+b)*256+j]);
      else if (sec==1) vv = fabsf(hb12[(size_t)b*256+j] - hb12[(size_t)(128+b)*256+j]);
      else if (sec==2) vv = fabsf(hfo[(size_t)b*256+j]  - h3f[(size_t)b*256+j]);
      else             vv = fabsf(hb12[(size_t)b*256+j] - hb3[(size_t)b*256+j]);
      dl[q][idx] = vv;
    }
  }
  __syncthreads();
  #pragma unroll
  for (int oo=0;oo<2;oo++){
    int o = tid + oo*256;
    float a0=fc1b[o], a1=a0, a2=a0, a3=a0;
    const float4* wr = (const float4*)(fc1w + (size_t)o*1024);
    for (int k4=0;k4<256;k4++){
      float4 w = wr[k4];
      float4 d0 = *(const float4*)&dl[0][k4*4];
      float4 d1 = *(const float4*)&dl[1][k4*4];
      float4 d2 = *(const float4*)&dl[2][k4*4];
      float4 d3 = *(const float4*)&dl[3][k4*4];
      a0 += w.x*d0.x + w.y*d0.y + w.z*d0.z + w.w*d0.w;
      a1 += w.x*d1.x + w.y*d1.y + w.z*d1.z + w.w*d1.w;
      a2 += w.x*d2.x + w.y*d2.y + w.z*d2.z + w.w*d2.w;
      a3 += w.x*d3.x + w.y*d3.y + w.z*d3.z + w.w*d3.w;
    }
    o1s[0][o]=fmaxf(a0,0.f); o1s[1][o]=fmaxf(a1,0.f);
    o1s[2][o]=fmaxf(a2,0.f); o1s[3][o]=fmaxf(a3,0.f);
  }
  __syncthreads();
  int qq = tid>>6, lq = tid&63;
  float s = 0.f;
  for (int k=lq;k<512;k+=64) s += o1s[qq][k]*fc2w[k];
  #pragma unroll
  for (int off=32;off;off>>=1) s += __shfl_down(s, off);
  if (lq==0) out[g*4+qq] = 1.f/(1.f+__expf(-(s+fc2b[0])));
}

extern "C" void kernel_launch(void* const* d_in, const int* in_sizes, int n_in,
                              void* d_out, int out_size, void* d_ws, size_t ws_size,
                              hipStream_t stream){
  (void)in_sizes; (void)n_in; (void)out_size;
  const float* x1    = (const float*)d_in[0];
  const float* x2    = (const float*)d_in[1];
  const float* dtime = (const float*)d_in[2];
  const float* c1w = (const float*)d_in[3];  const float* c1b = (const float*)d_in[4];
  const float* c3w = (const float*)d_in[5];  const float* c3b = (const float*)d_in[6];
  const float* c5w = (const float*)d_in[7];  const float* c5b = (const float*)d_in[8];
  const float* wihf = (const float*)d_in[9]; const float* whhf = (const float*)d_in[10];
  const float* bihf = (const float*)d_in[11];const float* bhhf = (const float*)d_in[12];
  const float* wihb = (const float*)d_in[13];
  const float* bihb = (const float*)d_in[15];const float* bhhb = (const float*)d_in[16];
  const float* fc1w = (const float*)d_in[17];const float* fc1b = (const float*)d_in[18];
  const float* fc2w = (const float*)d_in[19];const float* fc2b = (const float*)d_in[20];
  float* out = (float*)d_out;

  char* W = (char*)d_ws;
  float* xn      = (float*)(W);                 // 3,145,728
  float* x3n     = (float*)(W + 4194304);       // 6,144
  u16* wihf_p    = (u16*)(W + 5242880);         // 524,288
  u16* wihb_p    = (u16*)(W + 5767168);         // 524,288
  u16* whh_b     = (u16*)(W + 6291456);         // 524,288
  u16* hstate    = (u16*)(W + 6815744);         // 131,072
  float* cstate  = (float*)(W + 7340032);       // 262,144
  float* hfo     = (float*)(W + 8388608);       // 262,144
  float* hb12    = (float*)(W + 8650752);       // 262,144
  float* h3f     = (float*)(W + 8912896);       // 131,072
  float* hb3     = (float*)(W + 9043968);       // 131,072
  float* featF32 = (float*)(W + 9175040);       // 262,144 [256][256] f32
  float* xg3     = (float*)(W + 9437184);       // 1,048,576 [2][128][1024] f32
  u16* feat      = (u16*)(W + 10485760);        // 67,108,864 [131072][256]
  u16* xg        = (u16*)(W + 79691776);        // TB*524,288 bytes (bf16)

  size_t base = 79691776ull;
  int TB = 8;
  for (int tb=512; tb>=8; tb>>=1){
    if (base + (size_t)tb*524288ull <= ws_size){ TB = tb; break; }
  }
  int chunks = 512 / TB;

  k_prep<<<1024,256,0,stream>>>(wihf, wihb, whhf, wihf_p, wihb_p, whh_b);
  k_pre<<<128,256,0,stream>>>(x1, x2, dtime, xn, x3n);
  k_conv<<<256,256,0,stream>>>(xn, c1w,c1b,c3w,c3b,c5w,c5b, feat);
  k_x3fix<<<256,256,0,stream>>>(x3n, c1w,c1b,c3w,c3b,c5w,c5b, wihf, bihf, bhhf, xg3, featF32);
  k_b3fix<<<128,256,0,stream>>>(featF32, wihb, bihb, bhhb, hb3);
  k_bstep<<<16,512,0,stream>>>(wihb_p, bihb, bhhb, feat, 512, 511, hb12);
  k_lstm2f<<<8,512,0,stream>>>(whh_b, xg3, 2, 128, h3f);
  for (int c=0;c<chunks;c++){
    k_gemm2<<<TB*16,256,0,stream>>>(wihf_p, feat, bihf, bhhf, xg, c*TB);
    k_lstm2b<<<16,512,0,stream>>>(whh_b, xg, TB, (c==0)?1:0, (c==chunks-1)?1:0, hstate, cstate, hfo);
  }
  k_head<<<32,256,0,stream>>>(hfo, hb12, h3f, hb3, fc1w, fc1b, fc2w, fc2b, out);
}

// Round 10
// 2382.231 us; speedup vs baseline: 1.0590x; 1.0590x over previous
//
#include <hip/hip_runtime.h>
#include <math.h>

typedef unsigned short u16;
typedef unsigned int   u32;
typedef __attribute__((ext_vector_type(8))) short s8b;   // 8 bf16 (4 VGPR) MFMA frag
typedef __attribute__((ext_vector_type(4))) float f32x4; // MFMA acc

#define MFMA(a,b,c) __builtin_amdgcn_mfma_f32_16x16x32_bf16((a),(b),(c),0,0,0)

__device__ __forceinline__ float bf2f(u16 v){ return __uint_as_float(((u32)v)<<16); }
__device__ __forceinline__ u16 f2bf(float f){
    u32 u = __float_as_uint(f);
    u32 r = ((u>>16)&1u) + 0x7fffu;
    return (u16)((u + r)>>16);
}
__device__ __forceinline__ float rcp_(float x){ return __builtin_amdgcn_rcpf(x); }
__device__ __forceinline__ float sigm_(float x){ return rcp_(1.f + __expf(-x)); }
__device__ __forceinline__ float tanh_(float x){ return 1.f - 2.f*rcp_(1.f + __expf(2.f*x)); }

// ---------------- P0: weight prep (pad K 198->256, f32->bf16) ----------------
__global__ __launch_bounds__(256) void k_prep(const float* __restrict__ wihf,
    const float* __restrict__ wihb, const float* __restrict__ whhf,
    u16* __restrict__ wihf_p, u16* __restrict__ wihb_p, u16* __restrict__ whh_b){
  int idx = blockIdx.x*256 + threadIdx.x;
  if (idx >= 262144) return;
  int n = idx>>8, k = idx&255;
  wihf_p[idx] = (k<198)? f2bf(wihf[n*198+k]) : (u16)0;
  wihb_p[idx] = (k<198)? f2bf(wihb[n*198+k]) : (u16)0;
  whh_b[idx]  = f2bf(whhf[idx]);
}

// ---------------- K1: haversine + mercator normalize ----------------
__global__ __launch_bounds__(256) void k_pre(const float* __restrict__ x1,
    const float* __restrict__ x2, const float* __restrict__ dtime,
    float* __restrict__ xn, float* __restrict__ x3n){
  const float D2R = 0.017453292519943295f;
  const float R2D = 57.29577951308232f;
  const float RM  = 6378137.0f;
  const float PI4 = 0.7853981633974483f;
  int b = blockIdx.x, tid = threadIdx.x;
  __shared__ float red[256];
  float av[4], bv[4];
  #pragma unroll
  for (int j=0;j<2;j++){
    int l = tid + j*256;
    float la = x1[((size_t)b*512+l)*6+0], lo = x1[((size_t)b*512+l)*6+1];
    av[j]   = RM*(lo*D2R);
    bv[j]   = RM*logf(tanf(PI4 + la*D2R*0.5f));
    la = x2[((size_t)b*512+l)*6+0]; lo = x2[((size_t)b*512+l)*6+1];
    av[2+j] = RM*(lo*D2R);
    bv[2+j] = RM*logf(tanf(PI4 + la*D2R*0.5f));
  }
  float mxA,mnA,mxB,mnB,v;
  v = fmaxf(fmaxf(av[0],av[1]),fmaxf(av[2],av[3]));
  red[tid]=v; __syncthreads();
  for (int s=128;s;s>>=1){ if (tid<s) red[tid]=fmaxf(red[tid],red[tid+s]); __syncthreads(); }
  mxA = red[0]; __syncthreads();
  v = fminf(fminf(av[0],av[1]),fminf(av[2],av[3]));
  red[tid]=v; __syncthreads();
  for (int s=128;s;s>>=1){ if (tid<s) red[tid]=fminf(red[tid],red[tid+s]); __syncthreads(); }
  mnA = red[0]; __syncthreads();
  v = fmaxf(fmaxf(bv[0],bv[1]),fmaxf(bv[2],bv[3]));
  red[tid]=v; __syncthreads();
  for (int s=128;s;s>>=1){ if (tid<s) red[tid]=fmaxf(red[tid],red[tid+s]); __syncthreads(); }
  mxB = red[0]; __syncthreads();
  v = fminf(fminf(bv[0],bv[1]),fminf(bv[2],bv[3]));
  red[tid]=v; __syncthreads();
  for (int s=128;s;s>>=1){ if (tid<s) red[tid]=fminf(red[tid],red[tid+s]); __syncthreads(); }
  mnB = red[0];
  float dA = mxA-mnA+1e-8f, dB = mxB-mnB+1e-8f;
  float lat1 = x1[((size_t)b*512+511)*6+0], lon1 = x1[((size_t)b*512+511)*6+1];
  float lat2 = x2[((size_t)b*512+0)*6+0],   lon2 = x2[((size_t)b*512+0)*6+1];
  float la1=lat1*D2R, lo1=lon1*D2R, la2=lat2*D2R, lo2=lon2*D2R;
  float dlon=lo2-lo1, dlat=la2-la1;
  float sdlat=sinf(dlat*0.5f), sdlon=sinf(dlon*0.5f);
  float ah = sdlat*sdlat + cosf(la1)*cosf(la2)*sdlon*sdlon;
  float dist = 2.f*asinf(sqrtf(ah))*6371.0f;
  float yb = sinf(dlon)*cosf(la2);
  float xb = cosf(la1)*sinf(la2) - sinf(la1)*cosf(la2)*cosf(dlon);
  float brg = fmodf(atan2f(yb,xb)*R2D + 360.f, 360.f)*D2R;
  float dt = dtime[b]; if (dt==0.f) dt = 1.f;
  float speeds = dist/dt*1000.f/0.514444f;
  float vx = speeds*sinf(brg), vy = speeds*cosf(brg);
  #pragma unroll
  for (int j=0;j<2;j++){
    int l = tid + j*256;
    const float* s1 = x1 + ((size_t)b*512+l)*6;
    float* o1p = xn + ((size_t)b*512+l)*6;
    o1p[0] = (av[j]-mnA)/dA; o1p[1] = (bv[j]-mnB)/dB;
    o1p[2]=s1[2]; o1p[3]=s1[3]; o1p[4]=s1[4]; o1p[5]=s1[5];
    const float* s2 = x2 + ((size_t)b*512+l)*6;
    float* o2p = xn + ((size_t)(128+b)*512+l)*6;
    o2p[0] = (av[2+j]-mnA)/dA; o2p[1] = (bv[2+j]-mnB)/dB;
    float c2=s2[2], c3=s2[3], c4=s2[4], c5=s2[5];
    if (l==0){ c2 = (speeds!=0.f)?speeds:c2; c4 = (vx!=0.f)?vx:c4; c5 = (vy!=0.f)?vy:c5; }
    o2p[2]=c2; o2p[3]=c3; o2p[4]=c4; o2p[5]=c5;
  }
  if (tid==0){
    const float* r0 = x1 + ((size_t)b*512+511)*6;
    const float* r1 = x2 + ((size_t)b*512+0)*6;
    float* t0 = x3n + (size_t)b*12;
    float* t1 = t0 + 6;
    t0[0] = (RM*logf(tanf(PI4 + r0[0]*D2R*0.5f)) - mnA)/dA;
    t0[1] = (RM*(r0[1]*D2R) - mnB)/dB;
    t0[2]=r0[2]; t0[3]=r0[3]; t0[4]=r0[4]; t0[5]=r0[5];
    t1[0] = (RM*logf(tanf(PI4 + r1[0]*D2R*0.5f)) - mnA)/dA;
    t1[1] = (RM*(r1[1]*D2R) - mnB)/dB;
    float c2=r1[2], c4=r1[4], c5=r1[5];
    c2 = (speeds!=0.f)?speeds:c2; c4=(vx!=0.f)?vx:c4; c5=(vy!=0.f)?vy:c5;
    t1[2]=c2; t1[3]=r1[3]; t1[4]=c4; t1[5]=c5;
  }
}

// ---------------- K2: conv features -> feat [131072][256] bf16 ----------------
__global__ __launch_bounds__(256) void k_conv(const float* __restrict__ xn,
    const float* __restrict__ w1, const float* __restrict__ b1,
    const float* __restrict__ w3, const float* __restrict__ b3,
    const float* __restrict__ w5, const float* __restrict__ b5,
    u16* __restrict__ feat){
  int bb = blockIdx.x, tid = threadIdx.x;
  __shared__ float xs[516][7];
  __shared__ float ws[3648];
  for (int i=tid;i<516*6;i+=256){ int t=i/6-2, c=i%6;
    xs[i/6][c] = (t>=0 && t<512)? xn[((size_t)bb*512+t)*6+c] : 0.f; }
  for (int i=tid;i<3648;i+=256){
    float w;
    if (i<384) w=w1[i];
    else if (i<1536) w=w3[i-384];
    else if (i<3456) w=w5[i-1536];
    else if (i<3520) w=b1[i-3456];
    else if (i<3584) w=b3[i-3520];
    else w=b5[i-3584];
    ws[i]=w;
  }
  __syncthreads();
  int tl = tid & 127, hh = tid >> 7;
  for (int j=0;j<4;j++){
    int t = tl + j*128;
    u32* fru = (u32*)(feat + ((size_t)bb*512+t)*256);
    for (int p=0;p<16;p++){
      u32 pk=0;
      #pragma unroll
      for (int e=0;e<2;e++){
        int oc = 32*hh + p*2 + e;
        float acc = ws[3456+oc];
        #pragma unroll
        for (int i=0;i<6;i++) acc += xs[t+2][i]*ws[oc*6+i];
        pk |= ((u32)f2bf(fmaxf(acc,0.f)))<<(16*e);
      }
      fru[3+16*hh+p]=pk;
    }
    for (int p=0;p<16;p++){
      u32 pk=0;
      #pragma unroll
      for (int e=0;e<2;e++){
        int oc = 32*hh + p*2 + e;
        float acc = ws[3520+oc];
        #pragma unroll
        for (int k=0;k<3;k++)
          #pragma unroll
          for (int i=0;i<6;i++) acc += xs[t+1+k][i]*ws[384+oc*18+i*3+k];
        pk |= ((u32)f2bf(fmaxf(acc,0.f)))<<(16*e);
      }
      fru[35+16*hh+p]=pk;
    }
    for (int p=0;p<16;p++){
      u32 pk=0;
      #pragma unroll
      for (int e=0;e<2;e++){
        int oc = 32*hh + p*2 + e;
        float acc = ws[3584+oc];
        #pragma unroll
        for (int k=0;k<5;k++)
          #pragma unroll
          for (int i=0;i<6;i++) acc += xs[t+k][i]*ws[1536+oc*30+i*5+k];
        pk |= ((u32)f2bf(fmaxf(acc,0.f)))<<(16*e);
      }
      fru[67+16*hh+p]=pk;
    }
    if (hh==0){
      #pragma unroll
      for (int p=0;p<3;p++){
        u32 pk = (u32)f2bf(xs[t+2][2*p]) | (((u32)f2bf(xs[t+2][2*p+1]))<<16);
        fru[p]=pk;
      }
    } else {
      for (int p=99;p<128;p++) fru[p]=0u;
    }
  }
}

// ---------------- K2c: x3 branch, full f32 path (conv + xg with biases) ----------------
__global__ __launch_bounds__(256) void k_x3fix(const float* __restrict__ x3n,
    const float* __restrict__ w1, const float* __restrict__ b1,
    const float* __restrict__ w3, const float* __restrict__ b3,
    const float* __restrict__ w5, const float* __restrict__ b5,
    const float* __restrict__ wih, const float* __restrict__ bih, const float* __restrict__ bhh,
    float* __restrict__ xg3, float* __restrict__ featF32){
  int row = blockIdx.x, b = row>>1, t = row&1, tid = threadIdx.x;
  __shared__ float fl[224];
  __shared__ float xv[2][6];
  if (tid < 12) (&xv[0][0])[tid] = x3n[(size_t)b*12 + tid];
  __syncthreads();
  if (tid < 198){
    float v;
    if (tid < 6) v = xv[t][tid];
    else if (tid < 70){
      int oc = tid-6; float acc = b1[oc];
      #pragma unroll
      for (int i=0;i<6;i++) acc += xv[t][i]*w1[oc*6+i];
      v = fmaxf(acc,0.f);
    } else if (tid < 134){
      int oc = tid-70; float acc = b3[oc];
      for (int k=0;k<3;k++){ int tt=t+k-1; if (tt>=0&&tt<2)
        for (int i=0;i<6;i++) acc += xv[tt][i]*w3[oc*18+i*3+k]; }
      v = fmaxf(acc,0.f);
    } else {
      int oc = tid-134; float acc = b5[oc];
      for (int k=0;k<5;k++){ int tt=t+k-2; if (tt>=0&&tt<2)
        for (int i=0;i<6;i++) acc += xv[tt][i]*w5[oc*30+i*5+k]; }
      v = fmaxf(acc,0.f);
    }
    fl[tid]=v;
    featF32[(size_t)row*256+tid]=v;
  }
  __syncthreads();
  int n0 = tid*4;
  float a0=bih[n0]+bhh[n0], a1=bih[n0+1]+bhh[n0+1];
  float a2=bih[n0+2]+bhh[n0+2], a3=bih[n0+3]+bhh[n0+3];
  const float* w0 = wih + (size_t)n0*198;
  for (int k=0;k<198;k++){
    float f = fl[k];
    a0 += w0[k]*f; a1 += w0[198+k]*f; a2 += w0[396+k]*f; a3 += w0[594+k]*f;
  }
  float* op = xg3 + ((size_t)(t*128+b)<<10) + n0;
  op[0]=a0; op[1]=a1; op[2]=a2; op[3]=a3;
}

// ---------------- K2d: x3 backward single step, f32 ----------------
__global__ __launch_bounds__(256) void k_b3fix(const float* __restrict__ featF32,
    const float* __restrict__ wih, const float* __restrict__ bih, const float* __restrict__ bhh,
    float* __restrict__ hb3){
  int b = blockIdx.x, tid = threadIdx.x;
  __shared__ float fl[224];
  if (tid < 198) fl[tid] = featF32[(size_t)(2*b+1)*256 + tid];
  __syncthreads();
  int j = tid;
  float ai=bih[j]+bhh[j], ag=bih[512+j]+bhh[512+j], ao=bih[768+j]+bhh[768+j];
  const float* wi = wih + (size_t)j*198;
  const float* wg = wih + (size_t)(512+j)*198;
  const float* wo = wih + (size_t)(768+j)*198;
  for (int k=0;k<198;k++){
    float f = fl[k];
    ai += wi[k]*f; ag += wg[k]*f; ao += wo[k]*f;
  }
  float c = sigm_(ai)*tanh_(ag);
  hb3[(size_t)b*256 + j] = sigm_(ao)*tanh_(c);
}

// ---------------- K3: xg GEMM 128x128 tile, BK=64 -> bf16 out, LSTM-ordered layout ----------------
__global__ __launch_bounds__(256) void k_gemm2(const u16* __restrict__ Wp,
    const u16* __restrict__ F, const float* __restrict__ bih, const float* __restrict__ bhh,
    u16* __restrict__ outp, int t0){
  __shared__ u16 Wl[8192];  // [128][64] bf16, XOR-swizzled
  __shared__ u16 Fl[8192];
  int tid = threadIdx.x, wv = tid>>6, ln = tid&63;
  int kg = ln>>4, l15 = ln&15;
  int mb = blockIdx.x>>3, nb = blockIdx.x&7;
  int r = tid>>1, koffB = (tid&1)*64;
  int xr = (r&7)<<4;
  int mrow = mb*128 + r;
  int bbs = mrow&255, tls = mrow>>8;
  size_t frow = (size_t)bbs*512 + t0 + tls;
  const u16* gW = Wp + ((size_t)(nb*128 + r)<<8) + (koffB>>1);
  const u16* gF = F + (frow<<8) + (koffB>>1);
  f32x4 acc[4][4];
  #pragma unroll
  for (int wi=0;wi<4;wi++)
    #pragma unroll
    for (int fi=0;fi<4;fi++) acc[wi][fi] = (f32x4){0.f,0.f,0.f,0.f};
  int rowA = (wv&1)*64 + l15;
  int rowB = (wv>>1)*64 + l15;
  int xfr = (l15&7)<<4;
  for (int kt=0; kt<4; ++kt){
    uint4 wv4[4], fv4[4];
    #pragma unroll
    for (int q=0;q<4;q++){
      wv4[q] = *(const uint4*)(gW + kt*64 + q*8);
      fv4[q] = *(const uint4*)(gF + kt*64 + q*8);
    }
    if (kt) __syncthreads();
    #pragma unroll
    for (int q=0;q<4;q++){
      int byt = r*128 + ((koffB + q*16) ^ xr);
      *(uint4*)((char*)Wl + byt) = wv4[q];
      *(uint4*)((char*)Fl + byt) = fv4[q];
    }
    __syncthreads();
    #pragma unroll
    for (int ki=0;ki<2;ki++){
      s8b af[4], bfv[4];
      int kb = (ki*64 + kg*16) ^ xfr;
      #pragma unroll
      for (int wi=0;wi<4;wi++) af[wi]  = *(const s8b*)((char*)Wl + (rowA+wi*16)*128 + kb);
      #pragma unroll
      for (int fi=0;fi<4;fi++) bfv[fi] = *(const s8b*)((char*)Fl + (rowB+fi*16)*128 + kb);
      #pragma unroll
      for (int wi=0;wi<4;wi++)
        #pragma unroll
        for (int fi=0;fi<4;fi++)
          acc[wi][fi] = MFMA(af[wi], bfv[fi], acc[wi][fi]);
    }
  }
  #pragma unroll
  for (int wi=0;wi<4;wi++){
    int n0 = nb*128 + (wv&1)*64 + wi*16 + kg*4;
    float4 b1v = *(const float4*)(bih + n0);
    float4 b2v = *(const float4*)(bhh + n0);
    float bs0=b1v.x+b2v.x, bs1=b1v.y+b2v.y, bs2=b1v.z+b2v.z, bs3=b1v.w+b2v.w;
    int gt = n0>>8, jin = n0&255;
    int lwv = jin>>5, ljt = (jin>>4)&1, lkg = (jin>>2)&3;
    int csub = ((ljt*4+gt)*4+lkg)*64;
    #pragma unroll
    for (int fi=0;fi<4;fi++){
      int m = mb*128 + (wv>>1)*64 + fi*16 + l15;
      int bb = m&255, tl = m>>8;
      size_t e = (((size_t)tl*16 + (bb>>4))*8 + lwv)*2048 + csub + (bb&15)*4;
      uint2 pv;
      pv.x = (u32)f2bf(acc[wi][fi][0]+bs0) | (((u32)f2bf(acc[wi][fi][1]+bs1))<<16);
      pv.y = (u32)f2bf(acc[wi][fi][2]+bs2) | (((u32)f2bf(acc[wi][fi][3]+bs3))<<16);
      *(uint2*)(outp + e) = pv;
    }
  }
}

// ---------------- K4: backward single step (main), 512 thr ----------------
__global__ __launch_bounds__(512,1) void k_bstep(const u16* __restrict__ Wp,
    const float* __restrict__ bih, const float* __restrict__ bhh,
    const u16* __restrict__ feat, int row_stride, int row_off,
    float* __restrict__ hout){
  int tid = threadIdx.x, wv = tid>>6, ln = tid&63;
  int bcol = ln&15, kg = ln>>4;
  int bbase = blockIdx.x*16, jb = wv*32;
  size_t frowb = (size_t)(bbase+bcol)*row_stride + row_off;
  s8b ff[8];
  #pragma unroll
  for (int ki=0;ki<8;ki++) ff[ki] = *(const s8b*)(feat + frowb*256 + ki*32 + kg*8);
  const int gts[3] = {0,2,3};
  f32x4 acc[3][2];
  #pragma unroll
  for (int g3=0;g3<3;g3++)
    #pragma unroll
    for (int jt=0;jt<2;jt++)
      #pragma unroll
      for (int rr=0;rr<4;rr++){
        int n = gts[g3]*256 + jb + jt*16 + kg*4 + rr;
        acc[g3][jt][rr] = bih[n]+bhh[n];
      }
  #pragma unroll
  for (int ki=0;ki<8;ki++)
    #pragma unroll
    for (int g3=0;g3<3;g3++)
      #pragma unroll
      for (int jt=0;jt<2;jt++){
        s8b wfv = *(const s8b*)(Wp + ((size_t)(gts[g3]*256 + jb + jt*16 + bcol)<<8) + ki*32 + kg*8);
        acc[g3][jt] = MFMA(wfv, ff[ki], acc[g3][jt]);
      }
  #pragma unroll
  for (int jt=0;jt<2;jt++)
    #pragma unroll
    for (int rr=0;rr<4;rr++){
      float ig = sigm_(acc[0][jt][rr]);
      float gg = tanh_(acc[1][jt][rr]);
      float og = sigm_(acc[2][jt][rr]);
      float c  = ig*gg;
      hout[(size_t)(bbase+bcol)*256 + jb + jt*16 + kg*4 + rr] = og*tanh_(c);
    }
}

// ---------------- K5a: forward LSTM recurrence, bf16 xg, pinned 2 waves/SIMD ----------------
// amdgpu_waves_per_eu(2,2): hard-pin occupancy to the true value (8-wave block, grid=16
// -> 1 block/CU) so the allocator gets the full 256-reg unified budget and keeps
// wf[3][2][8] (192 regs) resident instead of targeting 128 regs for phantom occupancy.
__attribute__((amdgpu_waves_per_eu(2,2)))
__global__ __launch_bounds__(512) void k_lstm2b(
    const u16* __restrict__ Whh,      // [1024][256] bf16
    const u16* __restrict__ xgc,      // bf16, [t][wg][wv][2048] layout, biases folded
    int T, int first, int last,
    u16* __restrict__ hstate, float* __restrict__ cstate, float* __restrict__ hout){
  __shared__ u16 oW[65536];           // o-gate W [256][256], XOR-swizzled (128KB)
  __shared__ u16 hb[2][4096];         // h dbuf [16][256], XOR-swizzled (16KB)
  int tid = threadIdx.x, wv = tid>>6, ln = tid&63;
  int bcol = ln&15, kg = ln>>4;
  int bbase = blockIdx.x*16, jb = wv*32;
  int xb = (bcol&7)<<4;
  for (int c = tid; c < 8192; c += 512){
    int j = c>>5, kc = c&31;
    uint4 v = *(const uint4*)(Whh + ((size_t)(768+j)<<8) + (kc<<3));
    int byt = (j<<9) + ((kc<<4) ^ ((j&7)<<4));
    *(uint4*)((char*)oW + byt) = v;
  }
  {
    int c = tid;
    int b = c>>5, kc = c&31;
    uint4 v;
    if (first) v = (uint4){0u,0u,0u,0u};
    else v = *(const uint4*)(hstate + ((size_t)(bbase+b)<<8) + (kc<<3));
    int byt = (b<<9) + ((kc<<4) ^ ((b&7)<<4));
    *(uint4*)((char*)hb[0] + byt) = v;
  }
  s8b wf[3][2][8];
  #pragma unroll
  for (int gt=0;gt<3;gt++)
    #pragma unroll
    for (int jt=0;jt<2;jt++)
      #pragma unroll
      for (int ki=0;ki<8;ki++)
        wf[gt][jt][ki] = *(const s8b*)(Whh + ((size_t)(gt*256 + jb + jt*16 + bcol)<<8) + ki*32 + kg*8);
  // per-thread LDS byte offsets, step-invariant
  int koff[8];
  #pragma unroll
  for (int ki=0;ki<8;ki++) koff[ki] = (ki*64 + kg*16) ^ xb;
  int hb_base = bcol*512;
  int oW_base0 = (jb + 0*16 + bcol)*512;
  int oW_base1 = (jb + 1*16 + bcol)*512;
  float cst[2][4];
  #pragma unroll
  for (int jt=0;jt<2;jt++)
    #pragma unroll
    for (int rr=0;rr<4;rr++)
      cst[jt][rr] = first ? 0.f : cstate[((size_t)(bbase+bcol)<<8) + jb + jt*16 + kg*4 + rr];
  const u16* xrow = xgc + ((size_t)blockIdx.x*8 + wv)*2048 + kg*64 + bcol*4;
  uint2 xva[8];
  #pragma unroll
  for (int jt=0;jt<2;jt++)
    #pragma unroll
    for (int gt=0;gt<4;gt++)
      xva[jt*4+gt] = *(const uint2*)(xrow + (jt*4+gt)*256);
  __syncthreads();
  for (int t=0; t<T; ++t){
    char* hcur = (char*)hb[t&1];
    char* hnxt = (char*)hb[(t&1)^1];
    #pragma unroll
    for (int jt=0;jt<2;jt++){
      f32x4 a0 = {0.f,0.f,0.f,0.f};
      f32x4 a1 = {0.f,0.f,0.f,0.f};
      f32x4 a2 = {0.f,0.f,0.f,0.f};
      f32x4 a3 = {0.f,0.f,0.f,0.f};
      char* oWb = (char*)oW + (jt ? oW_base1 : oW_base0);
      #pragma unroll
      for (int ki=0;ki<8;ki++){
        s8b hf = *(const s8b*)(hcur + hb_base + koff[ki]);
        a0 = MFMA(wf[0][jt][ki], hf, a0);
        a1 = MFMA(wf[1][jt][ki], hf, a1);
        a2 = MFMA(wf[2][jt][ki], hf, a2);
        s8b of = *(const s8b*)(oWb + koff[ki]);
        a3 = MFMA(of, hf, a3);
      }
      uint2 x0 = xva[jt*4+0], x1v = xva[jt*4+1], x2v = xva[jt*4+2], x3v = xva[jt*4+3];
      float hv0, hv1, hv2, hv3;
      {
        float ig, fg, gg, og, c2;
        ig = sigm_(a0[0]+bf2f((u16)x0.x));  fg = sigm_(a1[0]+bf2f((u16)x1v.x));
        gg = tanh_(a2[0]+bf2f((u16)x2v.x)); og = sigm_(a3[0]+bf2f((u16)x3v.x));
        c2 = fg*cst[jt][0] + ig*gg; cst[jt][0] = c2; hv0 = og*tanh_(c2);
        ig = sigm_(a0[1]+bf2f((u16)(x0.x>>16)));  fg = sigm_(a1[1]+bf2f((u16)(x1v.x>>16)));
        gg = tanh_(a2[1]+bf2f((u16)(x2v.x>>16))); og = sigm_(a3[1]+bf2f((u16)(x3v.x>>16)));
        c2 = fg*cst[jt][1] + ig*gg; cst[jt][1] = c2; hv1 = og*tanh_(c2);
        ig = sigm_(a0[2]+bf2f((u16)x0.y));  fg = sigm_(a1[2]+bf2f((u16)x1v.y));
        gg = tanh_(a2[2]+bf2f((u16)x2v.y)); og = sigm_(a3[2]+bf2f((u16)x3v.y));
        c2 = fg*cst[jt][2] + ig*gg; cst[jt][2] = c2; hv2 = og*tanh_(c2);
        ig = sigm_(a0[3]+bf2f((u16)(x0.y>>16)));  fg = sigm_(a1[3]+bf2f((u16)(x1v.y>>16)));
        gg = tanh_(a2[3]+bf2f((u16)(x2v.y>>16))); og = sigm_(a3[3]+bf2f((u16)(x3v.y>>16)));
        c2 = fg*cst[jt][3] + ig*gg; cst[jt][3] = c2; hv3 = og*tanh_(c2);
      }
      if (last && t==T-1){
        float* op = hout + ((size_t)(bbase+bcol)<<8) + jb + jt*16 + kg*4;
        op[0]=hv0; op[1]=hv1; op[2]=hv2; op[3]=hv3;
      }
      uint2 hw;
      hw.x = (u32)f2bf(hv0) | (((u32)f2bf(hv1))<<16);
      hw.y = (u32)f2bf(hv2) | (((u32)f2bf(hv3))<<16);
      int wj = (jb + jt*16 + kg*4)*2;
      *(uint2*)(hnxt + hb_base + (wj ^ xb)) = hw;
    }
    if (t+1 < T){
      const u16* xp = xrow + (size_t)(t+1)*262144;
      #pragma unroll
      for (int jt=0;jt<2;jt++)
        #pragma unroll
        for (int gt=0;gt<4;gt++)
          xva[jt*4+gt] = *(const uint2*)(xp + (jt*4+gt)*256);
    }
    __syncthreads();
  }
  if (!last){
    char* hfin = (char*)hb[T&1];
    #pragma unroll
    for (int jt=0;jt<2;jt++){
      int wj = jb + jt*16 + kg*4;
      uint2 hw = *(const uint2*)(hfin + hb_base + ((wj*2) ^ xb));
      *(uint2*)(hstate + ((size_t)(bbase+bcol)<<8) + wj) = hw;
      float* cp = cstate + ((size_t)(bbase+bcol)<<8) + wj;
      cp[0]=cst[jt][0]; cp[1]=cst[jt][1]; cp[2]=cst[jt][2]; cp[3]=cst[jt][3];
    }
  }
}

// ---------------- K5b: forward LSTM recurrence, f32 xg (x3 branch only, T=2) ----------------
__attribute__((amdgpu_waves_per_eu(2,2)))
__global__ __launch_bounds__(512) void k_lstm2f(
    const u16* __restrict__ Whh,
    const float* __restrict__ xgc,    // [T][nbb][1024] f32
    int T, int nbb, float* __restrict__ hout){
  __shared__ u16 oW[65536];
  __shared__ u16 hb[2][4096];
  int tid = threadIdx.x, wv = tid>>6, ln = tid&63;
  int bcol = ln&15, kg = ln>>4;
  int bbase = blockIdx.x*16, jb = wv*32;
  int xb = (bcol&7)<<4;
  for (int c = tid; c < 8192; c += 512){
    int j = c>>5, kc = c&31;
    uint4 v = *(const uint4*)(Whh + ((size_t)(768+j)<<8) + (kc<<3));
    int byt = (j<<9) + ((kc<<4) ^ ((j&7)<<4));
    *(uint4*)((char*)oW + byt) = v;
  }
  {
    int c = tid;
    int b = c>>5, kc = c&31;
    uint4 v = (uint4){0u,0u,0u,0u};
    int byt = (b<<9) + ((kc<<4) ^ ((b&7)<<4));
    *(uint4*)((char*)hb[0] + byt) = v;
  }
  s8b wf[3][2][8];
  #pragma unroll
  for (int gt=0;gt<3;gt++)
    #pragma unroll
    for (int jt=0;jt<2;jt++)
      #pragma unroll
      for (int ki=0;ki<8;ki++)
        wf[gt][jt][ki] = *(const s8b*)(Whh + ((size_t)(gt*256 + jb + jt*16 + bcol)<<8) + ki*32 + kg*8);
  float cst[2][4];
  #pragma unroll
  for (int jt=0;jt<2;jt++)
    #pragma unroll
    for (int rr=0;rr<4;rr++) cst[jt][rr] = 0.f;
  __syncthreads();
  const float* xrow = xgc + ((size_t)(bbase+bcol)<<10) + jb;
  for (int t=0; t<T; ++t){
    const float* xp = xrow + (size_t)t*nbb*1024;
    char* hcur = (char*)hb[t&1];
    char* hnxt = (char*)hb[(t&1)^1];
    #pragma unroll
    for (int jt=0;jt<2;jt++){
      float4 xv0 = *(const float4*)(xp + 0*256 + jt*16 + kg*4);
      float4 xv1 = *(const float4*)(xp + 1*256 + jt*16 + kg*4);
      float4 xv2 = *(const float4*)(xp + 2*256 + jt*16 + kg*4);
      float4 xv3 = *(const float4*)(xp + 3*256 + jt*16 + kg*4);
      f32x4 a0 = {0.f,0.f,0.f,0.f};
      f32x4 a1 = {0.f,0.f,0.f,0.f};
      f32x4 a2 = {0.f,0.f,0.f,0.f};
      f32x4 a3 = {0.f,0.f,0.f,0.f};
      int j2 = jb + jt*16 + bcol;
      #pragma unroll
      for (int ki=0;ki<8;ki++){
        int kbyt = (ki*64 + kg*16) ^ xb;
        s8b hf = *(const s8b*)(hcur + bcol*512 + kbyt);
        a0 = MFMA(wf[0][jt][ki], hf, a0);
        a1 = MFMA(wf[1][jt][ki], hf, a1);
        a2 = MFMA(wf[2][jt][ki], hf, a2);
        s8b of = *(const s8b*)((char*)oW + j2*512 + kbyt);
        a3 = MFMA(of, hf, a3);
      }
      float hv0, hv1, hv2, hv3;
      {
        float ig, fg, gg, og, c2;
        ig = sigm_(a0[0]+xv0.x); fg = sigm_(a1[0]+xv1.x); gg = tanh_(a2[0]+xv2.x); og = sigm_(a3[0]+xv3.x);
        c2 = fg*cst[jt][0] + ig*gg; cst[jt][0] = c2; hv0 = og*tanh_(c2);
        ig = sigm_(a0[1]+xv0.y); fg = sigm_(a1[1]+xv1.y); gg = tanh_(a2[1]+xv2.y); og = sigm_(a3[1]+xv3.y);
        c2 = fg*cst[jt][1] + ig*gg; cst[jt][1] = c2; hv1 = og*tanh_(c2);
        ig = sigm_(a0[2]+xv0.z); fg = sigm_(a1[2]+xv1.z); gg = tanh_(a2[2]+xv2.z); og = sigm_(a3[2]+xv3.z);
        c2 = fg*cst[jt][2] + ig*gg; cst[jt][2] = c2; hv2 = og*tanh_(c2);
        ig = sigm_(a0[3]+xv0.w); fg = sigm_(a1[3]+xv1.w); gg = tanh_(a2[3]+xv2.w); og = sigm_(a3[3]+xv3.w);
        c2 = fg*cst[jt][3] + ig*gg; cst[jt][3] = c2; hv3 = og*tanh_(c2);
      }
      if (t==T-1){
        float* op = hout + ((size_t)(bbase+bcol)<<8) + jb + jt*16 + kg*4;
        op[0]=hv0; op[1]=hv1; op[2]=hv2; op[3]=hv3;
      }
      uint2 hw;
      hw.x = (u32)f2bf(hv0) | (((u32)f2bf(hv1))<<16);
      hw.y = (u32)f2bf(hv2) | (((u32)f2bf(hv3))<<16);
      int wj = (jb + jt*16 + kg*4)*2;
      *(uint2*)(hnxt + bcol*512 + (wj ^ xb)) = hw;
    }
    __syncthreads();
  }
}

// ---------------- K6: head ----------------
__global__ __launch_bounds__(256) void k_head(const float* __restrict__ hfo,
    const float* __restrict__ hb12, const float* __restrict__ h3f, const float* __restrict__ hb3,
    const float* __restrict__ fc1w, const float* __restrict__ fc1b,
    const float* __restrict__ fc2w, const float* __restrict__ fc2b,
    float* __restrict__ out){
  int g = blockIdx.x, tid = threadIdx.x;
  __shared__ float dl[4][1024];
  __shared__ float o1s[4][512];
  for (int q=0;q<4;q++){
    int b = g*4+q;
    for (int idx=tid; idx<1024; idx+=256){
      int sec = idx>>8, j = idx&255;
      float vv;
      if (sec==0)      vv = fabsf(hfo[(size_t)b*256+j]  - hfo[(size_t)(128+b)*256+j]);
      else if (sec==1) vv = fabsf(hb12[(size_t)b*256+j] - hb12[(size_t)(128+b)*256+j]);
      else if (sec==2) vv = fabsf(hfo[(size_t)b*256+j]  - h3f[(size_t)b*256+j]);
      else             vv = fabsf(hb12[(size_t)b*256+j] - hb3[(size_t)b*256+j]);
      dl[q][idx] = vv;
    }
  }
  __syncthreads();
  #pragma unroll
  for (int oo=0;oo<2;oo++){
    int o = tid + oo*256;
    float a0=fc1b[o], a1=a0, a2=a0, a3=a0;
    const float4* wr = (const float4*)(fc1w + (size_t)o*1024);
    for (int k4=0;k4<256;k4++){
      float4 w = wr[k4];
      float4 d0 = *(const float4*)&dl[0][k4*4];
      float4 d1 = *(const float4*)&dl[1][k4*4];
      float4 d2 = *(const float4*)&dl[2][k4*4];
      float4 d3 = *(const float4*)&dl[3][k4*4];
      a0 += w.x*d0.x + w.y*d0.y + w.z*d0.z + w.w*d0.w;
      a1 += w.x*d1.x + w.y*d1.y + w.z*d1.z + w.w*d1.w;
      a2 += w.x*d2.x + w.y*d2.y + w.z*d2.z + w.w*d2.w;
      a3 += w.x*d3.x + w.y*d3.y + w.z*d3.z + w.w*d3.w;
    }
    o1s[0][o]=fmaxf(a0,0.f); o1s[1][o]=fmaxf(a1,0.f);
    o1s[2][o]=fmaxf(a2,0.f); o1s[3][o]=fmaxf(a3,0.f);
  }
  __syncthreads();
  int qq = tid>>6, lq = tid&63;
  float s = 0.f;
  for (int k=lq;k<512;k+=64) s += o1s[qq][k]*fc2w[k];
  #pragma unroll
  for (int off=32;off;off>>=1) s += __shfl_down(s, off);
  if (lq==0) out[g*4+qq] = 1.f/(1.f+__expf(-(s+fc2b[0])));
}

extern "C" void kernel_launch(void* const* d_in, const int* in_sizes, int n_in,
                              void* d_out, int out_size, void* d_ws, size_t ws_size,
                              hipStream_t stream){
  (void)in_sizes; (void)n_in; (void)out_size;
  const float* x1    = (const float*)d_in[0];
  const float* x2    = (const float*)d_in[1];
  const float* dtime = (const float*)d_in[2];
  const float* c1w = (const float*)d_in[3];  const float* c1b = (const float*)d_in[4];
  const float* c3w = (const float*)d_in[5];  const float* c3b = (const float*)d_in[6];
  const float* c5w = (const float*)d_in[7];  const float* c5b = (const float*)d_in[8];
  const float* wihf = (const float*)d_in[9]; const float* whhf = (const float*)d_in[10];
  const float* bihf = (const float*)d_in[11];const float* bhhf = (const float*)d_in[12];
  const float* wihb = (const float*)d_in[13];
  const float* bihb = (const float*)d_in[15];const float* bhhb = (const float*)d_in[16];
  const float* fc1w = (const float*)d_in[17];const float* fc1b = (const float*)d_in[18];
  const float* fc2w = (const float*)d_in[19];const float* fc2b = (const float*)d_in[20];
  float* out = (float*)d_out;

  char* W = (char*)d_ws;
  float* xn      = (float*)(W);                 // 3,145,728
  float* x3n     = (float*)(W + 4194304);       // 6,144
  u16* wihf_p    = (u16*)(W + 5242880);         // 524,288
  u16* wihb_p    = (u16*)(W + 5767168);         // 524,288
  u16* whh_b     = (u16*)(W + 6291456);         // 524,288
  u16* hstate    = (u16*)(W + 6815744);         // 131,072
  float* cstate  = (float*)(W + 7340032);       // 262,144
  float* hfo     = (float*)(W + 8388608);       // 262,144
  float* hb12    = (float*)(W + 8650752);       // 262,144
  float* h3f     = (float*)(W + 8912896);       // 131,072
  float* hb3     = (float*)(W + 9043968);       // 131,072
  float* featF32 = (float*)(W + 9175040);       // 262,144 [256][256] f32
  float* xg3     = (float*)(W + 9437184);       // 1,048,576 [2][128][1024] f32
  u16* feat      = (u16*)(W + 10485760);        // 67,108,864 [131072][256]
  u16* xg        = (u16*)(W + 79691776);        // TB*524,288 bytes (bf16)

  size_t base = 79691776ull;
  int TB = 8;
  for (int tb=512; tb>=8; tb>>=1){
    if (base + (size_t)tb*524288ull <= ws_size){ TB = tb; break; }
  }
  int chunks = 512 / TB;

  k_prep<<<1024,256,0,stream>>>(wihf, wihb, whhf, wihf_p, wihb_p, whh_b);
  k_pre<<<128,256,0,stream>>>(x1, x2, dtime, xn, x3n);
  k_conv<<<256,256,0,stream>>>(xn, c1w,c1b,c3w,c3b,c5w,c5b, feat);
  k_x3fix<<<256,256,0,stream>>>(x3n, c1w,c1b,c3w,c3b,c5w,c5b, wihf, bihf, bhhf, xg3, featF32);
  k_b3fix<<<128,256,0,stream>>>(featF32, wihb, bihb, bhhb, hb3);
  k_bstep<<<16,512,0,stream>>>(wihb_p, bihb, bhhb, feat, 512, 511, hb12);
  k_lstm2f<<<8,512,0,stream>>>(whh_b, xg3, 2, 128, h3f);
  for (int c=0;c<chunks;c++){
    k_gemm2<<<TB*16,256,0,stream>>>(wihf_p, feat, bihf, bhhf, xg, c*TB);
    k_lstm2b<<<16,512,0,stream>>>(whh_b, xg, TB, (c==0)?1:0, (c==chunks-1)?1:0, hstate, cstate, hfo);
  }
  k_head<<<32,256,0,stream>>>(hfo, hb12, h3f, hb3, fc1w, fc1b, fc2w, fc2b, out);
}